// Round 1
// baseline (653.873 us; speedup 1.0000x reference)
//
#include <hip/hip_runtime.h>
#include <stdint.h>

typedef __attribute__((ext_vector_type(8))) short bf16x8;
typedef __attribute__((ext_vector_type(4))) float f32x4;

#define NF 256
#define NH 256
#define KTOT 512
#define BM 128
#define BN 128
#define BK 32
#define LDP 40   // padded LDS row stride (elems): 80B -> bank-conflict-light

static __device__ __forceinline__ float bf2f(unsigned short u){
  union { unsigned int i; float f; } v; v.i = ((unsigned int)u) << 16; return v.f;
}
static __device__ __forceinline__ unsigned short f2bf(float f){
  union { float f; unsigned int u; } v; v.f = f;
  unsigned int r = v.u + 0x7fffu + ((v.u >> 16) & 1u);   // RNE
  return (unsigned short)(r >> 16);
}

// ---- K1: x f32 -> bf16 (8 elems/thread, float4 loads) ----
__global__ void k_cvt_x(const float* __restrict__ x, unsigned short* __restrict__ xb, int n8){
  for (int i = blockIdx.x*blockDim.x + threadIdx.x; i < n8; i += gridDim.x*blockDim.x){
    const float4* p = (const float4*)(x + (size_t)i*8);
    float4 a = p[0], b = p[1];
    ushort4 o0, o1;
    o0.x=f2bf(a.x); o0.y=f2bf(a.y); o0.z=f2bf(a.z); o0.w=f2bf(a.w);
    o1.x=f2bf(b.x); o1.y=f2bf(b.y); o1.z=f2bf(b.z); o1.w=f2bf(b.w);
    ushort4* q = (ushort4*)(xb + (size_t)i*8);
    q[0] = o0; q[1] = o1;
  }
}

// ---- K2: build transposed+concat weight Wt[n][k] = k<256 ? Ws[k][n] : Wn[k-256][n] ----
__global__ void k_cvt_w(const float* __restrict__ Ws, const float* __restrict__ Wn,
                        unsigned short* __restrict__ Wt){
  int t = blockIdx.x*blockDim.x + threadIdx.x;
  if (t >= NH*KTOT) return;
  int n = t >> 9, k = t & 511;
  float v = (k < NF) ? Ws[(size_t)k*NH + n] : Wn[(size_t)(k-NF)*NH + n];
  Wt[t] = f2bf(v);
}

// ---- K3: degree histogram ----
__global__ void k_hist(const int* __restrict__ dst, int* __restrict__ deg, int ne){
  for (int e = blockIdx.x*blockDim.x + threadIdx.x; e < ne; e += gridDim.x*blockDim.x)
    atomicAdd(&deg[dst[e]], 1);
}

// ---- K4a: per-block (1024-chunk) sums ----
__global__ void k_partial(const int* __restrict__ deg, int* __restrict__ partial, int n){
  __shared__ int sm[256];
  int b = blockIdx.x, t = threadIdx.x;
  int i0 = b*1024 + t*4;
  int s = 0;
  if (i0 + 3 < n){ int4 v = *(const int4*)(deg + i0); s = v.x+v.y+v.z+v.w; }
  else { for (int j=0;j<4;j++) if (i0+j < n) s += deg[i0+j]; }
  sm[t] = s; __syncthreads();
  for (int d = 128; d > 0; d >>= 1){ if (t < d) sm[t] += sm[t+d]; __syncthreads(); }
  if (t == 0) partial[b] = sm[0];
}

// ---- K4b: exclusive scan of partials (1 block; nb <= 128) ----
__global__ void k_scanp(int* __restrict__ partial, int nb){
  __shared__ int sm[128];
  int t = threadIdx.x;
  int v = (t < nb) ? partial[t] : 0;
  sm[t] = v; __syncthreads();
  for (int d = 1; d < 128; d <<= 1){
    int u = (t >= d) ? sm[t-d] : 0; __syncthreads();
    sm[t] += u; __syncthreads();
  }
  if (t < nb) partial[t] = sm[t] - v;
}

// ---- K4c: apply scan -> CSR row offsets ----
__global__ void k_scanapply(const int* __restrict__ deg, const int* __restrict__ partial,
                            int* __restrict__ off, int n, int ne){
  __shared__ int sm[256];
  int b = blockIdx.x, t = threadIdx.x;
  int i0 = b*1024 + t*4;
  int d0=0,d1=0,d2=0,d3=0;
  if (i0 + 3 < n){ int4 v = *(const int4*)(deg + i0); d0=v.x; d1=v.y; d2=v.z; d3=v.w; }
  else { if(i0<n)d0=deg[i0]; if(i0+1<n)d1=deg[i0+1]; if(i0+2<n)d2=deg[i0+2]; if(i0+3<n)d3=deg[i0+3]; }
  int s = d0+d1+d2+d3;
  sm[t] = s; __syncthreads();
  for (int d = 1; d < 256; d <<= 1){
    int u = (t >= d) ? sm[t-d] : 0; __syncthreads();
    sm[t] += u; __syncthreads();
  }
  int run = partial[b] + sm[t] - s;
  if (i0   < n) off[i0]   = run; run += d0;
  if (i0+1 < n) off[i0+1] = run; run += d1;
  if (i0+2 < n) off[i0+2] = run; run += d2;
  if (i0+3 < n) off[i0+3] = run;
  if (b == 0 && t == 0) off[n] = ne;
}

// ---- K5: bucket-scatter edges into CSR ----
__global__ void k_scatter(const int* __restrict__ src, const int* __restrict__ dst,
                          const int* __restrict__ off, int* __restrict__ cur,
                          int* __restrict__ col, int ne){
  for (int e = blockIdx.x*blockDim.x + threadIdx.x; e < ne; e += gridDim.x*blockDim.x){
    int d = dst[e];
    int p = off[d] + atomicAdd(&cur[d], 1);
    col[p] = src[e];
  }
}

// ---- K6: pull-aggregation, one wave per dst node, mean -> hb (bf16) ----
__global__ void __launch_bounds__(256) k_agg(const unsigned short* __restrict__ xb,
                                             const int* __restrict__ off,
                                             const int* __restrict__ col,
                                             unsigned short* __restrict__ hb, int n){
  int w = threadIdx.x >> 6;
  int lane = threadIdx.x & 63;
  int node = blockIdx.x*4 + w;
  if (node >= n) return;
  int e0 = off[node], e1 = off[node+1];
  float a0=0.f, a1=0.f, a2=0.f, a3=0.f;
  int e = e0;
  for (; e + 1 < e1; e += 2){
    int s0 = col[e], s1 = col[e+1];
    ushort4 v0 = ((const ushort4*)(xb + (size_t)s0*NF))[lane];
    ushort4 v1 = ((const ushort4*)(xb + (size_t)s1*NF))[lane];
    a0 += bf2f(v0.x) + bf2f(v1.x);
    a1 += bf2f(v0.y) + bf2f(v1.y);
    a2 += bf2f(v0.z) + bf2f(v1.z);
    a3 += bf2f(v0.w) + bf2f(v1.w);
  }
  if (e < e1){
    int s0 = col[e];
    ushort4 v0 = ((const ushort4*)(xb + (size_t)s0*NF))[lane];
    a0 += bf2f(v0.x); a1 += bf2f(v0.y); a2 += bf2f(v0.z); a3 += bf2f(v0.w);
  }
  float inv = 1.f / (float)((e1 - e0) > 1 ? (e1 - e0) : 1);
  ushort4 o;
  o.x = f2bf(a0*inv); o.y = f2bf(a1*inv); o.z = f2bf(a2*inv); o.w = f2bf(a3*inv);
  ((ushort4*)(hb + (size_t)node*NF))[lane] = o;
}

// ---- K7: out = relu([xb, hb] @ Wt^T + b), 128x128 tile, 4 waves x 64x64 ----
__global__ void __launch_bounds__(256) k_gemm(const unsigned short* __restrict__ xb,
                                              const unsigned short* __restrict__ hb,
                                              const unsigned short* __restrict__ Wt,
                                              const float* __restrict__ bias,
                                              float* __restrict__ out, int M){
  __shared__ unsigned short As[BM*LDP];
  __shared__ unsigned short Bs[BN*LDP];
  int t = threadIdx.x;
  int m0 = blockIdx.x * BM;
  int n0 = blockIdx.y * BN;
  int w = t >> 6, lane = t & 63;
  int wm = w >> 1, wn = w & 1;
  int lrow = lane & 15, k8 = (lane >> 4) * 8;

  f32x4 acc[4][4];
  #pragma unroll
  for (int i=0;i<4;i++)
    #pragma unroll
    for (int j=0;j<4;j++) acc[i][j] = (f32x4){0.f,0.f,0.f,0.f};

  for (int kk = 0; kk < KTOT; kk += BK){
    __syncthreads();
    const unsigned short* Asrc = (kk < NF) ? (xb + kk) : (hb + (kk - NF));
    #pragma unroll
    for (int p = 0; p < 2; p++){
      int f = p*256 + t;
      int r = f >> 2, c = (f & 3) * 8;
      int gr = m0 + r; if (gr > M-1) gr = M-1;
      int4 v = *(const int4*)(Asrc + (size_t)gr*NF + c);
      *(int4*)(&As[r*LDP + c]) = v;
    }
    #pragma unroll
    for (int p = 0; p < 2; p++){
      int f = p*256 + t;
      int r = f >> 2, c = (f & 3) * 8;
      int4 v = *(const int4*)(Wt + (size_t)(n0 + r)*KTOT + kk + c);
      *(int4*)(&Bs[r*LDP + c]) = v;
    }
    __syncthreads();
    bf16x8 af[4], bfr[4];
    #pragma unroll
    for (int mi=0;mi<4;mi++)
      af[mi] = *(const bf16x8*)(&As[(wm*64 + mi*16 + lrow)*LDP + k8]);
    #pragma unroll
    for (int ni=0;ni<4;ni++)
      bfr[ni] = *(const bf16x8*)(&Bs[(wn*64 + ni*16 + lrow)*LDP + k8]);
    #pragma unroll
    for (int mi=0;mi<4;mi++)
      #pragma unroll
      for (int ni=0;ni<4;ni++)
        acc[mi][ni] = __builtin_amdgcn_mfma_f32_16x16x32_bf16(af[mi], bfr[ni], acc[mi][ni], 0, 0, 0);
  }

  #pragma unroll
  for (int ni=0;ni<4;ni++){
    int cn = n0 + wn*64 + ni*16 + lrow;
    float bv = bias[cn];
    #pragma unroll
    for (int mi=0;mi<4;mi++){
      #pragma unroll
      for (int r=0;r<4;r++){
        int rm = m0 + wm*64 + mi*16 + (lane>>4)*4 + r;
        if (rm < M){
          float v = acc[mi][ni][r] + bv;
          out[(size_t)rm*NH + cn] = v > 0.f ? v : 0.f;
        }
      }
    }
  }
}

extern "C" void kernel_launch(void* const* d_in, const int* in_sizes, int n_in,
                              void* d_out, int out_size, void* d_ws, size_t ws_size,
                              hipStream_t stream){
  const float* x      = (const float*)d_in[0];
  const float* Wself  = (const float*)d_in[1];
  const float* Wneigh = (const float*)d_in[2];
  const float* bias   = (const float*)d_in[3];
  const int*   esrc   = (const int*)d_in[4];
  const int*   edst   = (const int*)d_in[5];
  const int nn = in_sizes[0] / NF;   // 100000
  const int ne = in_sizes[4];        // 3200000

  // workspace carve-up (~117 MB total)
  char* w = (char*)d_ws;
  auto alloc = [&](size_t bytes)->char*{
    char* p = w; w += (bytes + 511) & ~size_t(511); return p;
  };
  unsigned short* xb  = (unsigned short*)alloc((size_t)nn*NF*2);
  unsigned short* hb  = (unsigned short*)alloc((size_t)nn*NF*2);
  int* col            = (int*)alloc((size_t)ne*4);
  int* deg            = (int*)alloc((size_t)nn*4);
  int* off            = (int*)alloc((size_t)(nn+1)*4);
  int* cur            = (int*)alloc((size_t)nn*4);
  unsigned short* Wt  = (unsigned short*)alloc((size_t)NH*KTOT*2);
  int* partial        = (int*)alloc(4096);

  hipMemsetAsync(deg, 0, (size_t)nn*4, stream);
  hipMemsetAsync(cur, 0, (size_t)nn*4, stream);

  k_cvt_x<<<2048, 256, 0, stream>>>(x, xb, nn*NF/8);
  k_cvt_w<<<(NH*KTOT + 255)/256, 256, 0, stream>>>(Wself, Wneigh, Wt);
  k_hist<<<2048, 256, 0, stream>>>(edst, deg, ne);
  int nb = (nn + 1023) / 1024;  // 98
  k_partial<<<nb, 256, 0, stream>>>(deg, partial, nn);
  k_scanp<<<1, 128, 0, stream>>>(partial, nb);
  k_scanapply<<<nb, 256, 0, stream>>>(deg, partial, off, nn, ne);
  k_scatter<<<2048, 256, 0, stream>>>(esrc, edst, off, cur, col, ne);
  k_agg<<<(nn + 3)/4, 256, 0, stream>>>(xb, off, col, hb, nn);
  dim3 gg((nn + BM - 1)/BM, NH/BN);
  k_gemm<<<gg, 256, 0, stream>>>(xb, hb, Wt, bias, (float*)d_out, nn);
}

// Round 2
// 462.970 us; speedup vs baseline: 1.4123x; 1.4123x over previous
//
#include <hip/hip_runtime.h>
#include <stdint.h>

typedef __attribute__((ext_vector_type(8))) short bf16x8;
typedef __attribute__((ext_vector_type(4))) float f32x4;
typedef __attribute__((ext_vector_type(2))) float f32x2;

#define NF 256
#define NH 256
#define KTOT 512
#define BM 128
#define BN 128
#define BK 32
#define LDP 40   // padded LDS row stride (elems): 80B -> bank-conflict-light

static __device__ __forceinline__ float bf2f(unsigned short u){
  union { unsigned int i; float f; } v; v.i = ((unsigned int)u) << 16; return v.f;
}
static __device__ __forceinline__ unsigned short f2bf(float f){
  union { float f; unsigned int u; } v; v.f = f;
  unsigned int r = v.u + 0x7fffu + ((v.u >> 16) & 1u);   // RNE
  return (unsigned short)(r >> 16);
}
// f32 -> OCP e4m3fn (RNE, FTZ below 2^-6, saturate at 448)
static __device__ __forceinline__ unsigned int f2e4(float f){
  union { float f; unsigned int u; } v; v.f = f;
  unsigned int s = v.u >> 31;
  unsigned int mag = v.u & 0x7fffffffu;
  if (mag > 0x43E00000u) mag = 0x43E00000u;           // clamp to 448
  unsigned int r = mag + 0x7ffffu + ((mag >> 20) & 1u); // RNE at 3 mantissa bits
  if (r < 0x3C800000u) return 0u;                     // below 2^-6 -> 0
  return (s << 7) | (((r >> 20) - 960u) & 0x7fu);
}

// ---- K1: x f32 -> fp8 e4m3 (8 elems/thread) ----
__global__ void k_cvt_xq(const float* __restrict__ x, unsigned int* __restrict__ xq, int n8){
  for (int i = blockIdx.x*blockDim.x + threadIdx.x; i < n8; i += gridDim.x*blockDim.x){
    const float4* p = (const float4*)(x + (size_t)i*8);
    float4 a = p[0], b = p[1];
    unsigned int w0 = f2e4(a.x) | (f2e4(a.y)<<8) | (f2e4(a.z)<<16) | (f2e4(a.w)<<24);
    unsigned int w1 = f2e4(b.x) | (f2e4(b.y)<<8) | (f2e4(b.z)<<16) | (f2e4(b.w)<<24);
    uint2 o; o.x = w0; o.y = w1;
    ((uint2*)xq)[i] = o;
  }
}

// ---- K2: build transposed+concat weight Wt[n][k] = k<256 ? Ws[k][n] : Wn[k-256][n] ----
__global__ void k_cvt_w(const float* __restrict__ Ws, const float* __restrict__ Wn,
                        unsigned short* __restrict__ Wt){
  int t = blockIdx.x*blockDim.x + threadIdx.x;
  if (t >= NH*KTOT) return;
  int n = t >> 9, k = t & 511;
  float v = (k < NF) ? Ws[(size_t)k*NH + n] : Wn[(size_t)(k-NF)*NH + n];
  Wt[t] = (unsigned short)f2bf(v);
}

// ---- K3: degree histogram + per-edge rank (one atomic pass total) ----
__global__ void k_rank(const int* __restrict__ dst, int* __restrict__ deg,
                       int* __restrict__ rank, int ne){
  for (int e = blockIdx.x*blockDim.x + threadIdx.x; e < ne; e += gridDim.x*blockDim.x)
    rank[e] = atomicAdd(&deg[dst[e]], 1);
}

// ---- K4a: per-block (1024-chunk) sums ----
__global__ void k_partial(const int* __restrict__ deg, int* __restrict__ partial, int n){
  __shared__ int sm[256];
  int b = blockIdx.x, t = threadIdx.x;
  int i0 = b*1024 + t*4;
  int s = 0;
  if (i0 + 3 < n){ int4 v = *(const int4*)(deg + i0); s = v.x+v.y+v.z+v.w; }
  else { for (int j=0;j<4;j++) if (i0+j < n) s += deg[i0+j]; }
  sm[t] = s; __syncthreads();
  for (int d = 128; d > 0; d >>= 1){ if (t < d) sm[t] += sm[t+d]; __syncthreads(); }
  if (t == 0) partial[b] = sm[0];
}

// ---- K4b: exclusive scan of partials (1 block; nb <= 128) ----
__global__ void k_scanp(int* __restrict__ partial, int nb){
  __shared__ int sm[128];
  int t = threadIdx.x;
  int v = (t < nb) ? partial[t] : 0;
  sm[t] = v; __syncthreads();
  for (int d = 1; d < 128; d <<= 1){
    int u = (t >= d) ? sm[t-d] : 0; __syncthreads();
    sm[t] += u; __syncthreads();
  }
  if (t < nb) partial[t] = sm[t] - v;
}

// ---- K4c: apply scan -> CSR row offsets ----
__global__ void k_scanapply(const int* __restrict__ deg, const int* __restrict__ partial,
                            int* __restrict__ off, int n, int ne){
  __shared__ int sm[256];
  int b = blockIdx.x, t = threadIdx.x;
  int i0 = b*1024 + t*4;
  int d0=0,d1=0,d2=0,d3=0;
  if (i0 + 3 < n){ int4 v = *(const int4*)(deg + i0); d0=v.x; d1=v.y; d2=v.z; d3=v.w; }
  else { if(i0<n)d0=deg[i0]; if(i0+1<n)d1=deg[i0+1]; if(i0+2<n)d2=deg[i0+2]; if(i0+3<n)d3=deg[i0+3]; }
  int s = d0+d1+d2+d3;
  sm[t] = s; __syncthreads();
  for (int d = 1; d < 256; d <<= 1){
    int u = (t >= d) ? sm[t-d] : 0; __syncthreads();
    sm[t] += u; __syncthreads();
  }
  int run = partial[b] + sm[t] - s;
  if (i0   < n) off[i0]   = run; run += d0;
  if (i0+1 < n) off[i0+1] = run; run += d1;
  if (i0+2 < n) off[i0+2] = run; run += d2;
  if (i0+3 < n) off[i0+3] = run;
  if (b == 0 && t == 0) off[n] = ne;
}

// ---- K5: scatter edges into CSR (no atomics — rank precomputed) ----
__global__ void k_scatter(const int* __restrict__ src, const int* __restrict__ dst,
                          const int* __restrict__ rank, const int* __restrict__ off,
                          int* __restrict__ col, int ne){
  for (int e = blockIdx.x*blockDim.x + threadIdx.x; e < ne; e += gridDim.x*blockDim.x){
    col[off[dst[e]] + rank[e]] = src[e];
  }
}

// ---- fp8x4 word -> 4 f32 accumulate ----
static __device__ __forceinline__ void acc4(unsigned int v, float& a0, float& a1, float& a2, float& a3){
#if __has_builtin(__builtin_amdgcn_cvt_pk_f32_fp8)
  f32x2 lo = __builtin_amdgcn_cvt_pk_f32_fp8((int)v, false);
  f32x2 hi = __builtin_amdgcn_cvt_pk_f32_fp8((int)v, true);
  a0 += lo[0]; a1 += lo[1]; a2 += hi[0]; a3 += hi[1];
#else
  #pragma unroll
  for (int j = 0; j < 4; j++){
    unsigned int b = (v >> (8*j)) & 0xffu;
    unsigned int tt = b & 0x7fu;
    union { unsigned int u; float f; } w;
    w.u = ((tt + 960u) << 20) | ((b & 0x80u) << 24);
    float f = tt ? w.f : 0.f;
    if (j==0) a0 += f; else if (j==1) a1 += f; else if (j==2) a2 += f; else a3 += f;
  }
#endif
}

// ---- K6: pull-aggregation over fp8 x, one wave per dst node, mean -> hb (bf16) ----
__global__ void __launch_bounds__(256) k_agg(const unsigned char* __restrict__ xq,
                                             const int* __restrict__ off,
                                             const int* __restrict__ col,
                                             unsigned short* __restrict__ hb, int n){
  int w = threadIdx.x >> 6;
  int lane = threadIdx.x & 63;
  int node = blockIdx.x*4 + w;
  if (node >= n) return;
  int e0 = off[node], e1 = off[node+1];
  float a0=0.f, a1=0.f, a2=0.f, a3=0.f;
  int e = e0;
  for (; e + 3 < e1; e += 4){
    int s0 = col[e], s1 = col[e+1], s2 = col[e+2], s3 = col[e+3];
    unsigned int v0 = ((const unsigned int*)(xq + (size_t)s0*NF))[lane];
    unsigned int v1 = ((const unsigned int*)(xq + (size_t)s1*NF))[lane];
    unsigned int v2 = ((const unsigned int*)(xq + (size_t)s2*NF))[lane];
    unsigned int v3 = ((const unsigned int*)(xq + (size_t)s3*NF))[lane];
    acc4(v0, a0,a1,a2,a3);
    acc4(v1, a0,a1,a2,a3);
    acc4(v2, a0,a1,a2,a3);
    acc4(v3, a0,a1,a2,a3);
  }
  for (; e < e1; e++){
    int s0 = col[e];
    unsigned int v0 = ((const unsigned int*)(xq + (size_t)s0*NF))[lane];
    acc4(v0, a0,a1,a2,a3);
  }
  float inv = 1.f / (float)((e1 - e0) > 1 ? (e1 - e0) : 1);
  ushort4 o;
  o.x = f2bf(a0*inv); o.y = f2bf(a1*inv); o.z = f2bf(a2*inv); o.w = f2bf(a3*inv);
  ((ushort4*)(hb + (size_t)node*NF))[lane] = o;
}

// ---- K7: out = relu([x, h] @ Wt^T + b); A self-half staged from f32 x, neigh-half from bf16 hb ----
__global__ void __launch_bounds__(256) k_gemm(const float* __restrict__ xf,
                                              const unsigned short* __restrict__ hb,
                                              const unsigned short* __restrict__ Wt,
                                              const float* __restrict__ bias,
                                              float* __restrict__ out, int M){
  __shared__ unsigned short As[BM*LDP];
  __shared__ unsigned short Bs[BN*LDP];
  int t = threadIdx.x;
  int m0 = blockIdx.x * BM;
  int n0 = blockIdx.y * BN;
  int w = t >> 6, lane = t & 63;
  int wm = w >> 1, wn = w & 1;
  int lrow = lane & 15, k8 = (lane >> 4) * 8;

  f32x4 acc[4][4];
  #pragma unroll
  for (int i=0;i<4;i++)
    #pragma unroll
    for (int j=0;j<4;j++) acc[i][j] = (f32x4){0.f,0.f,0.f,0.f};

  for (int kk = 0; kk < KTOT; kk += BK){
    __syncthreads();
    if (kk < NF){
      #pragma unroll
      for (int p = 0; p < 2; p++){
        int f = p*256 + t;
        int r = f >> 2, c = (f & 3) * 8;
        int gr = m0 + r; if (gr > M-1) gr = M-1;
        const float* src = xf + (size_t)gr*NF + kk + c;
        float4 u0 = *(const float4*)src;
        float4 u1 = *(const float4*)(src + 4);
        ushort4 o0, o1;
        o0.x=f2bf(u0.x); o0.y=f2bf(u0.y); o0.z=f2bf(u0.z); o0.w=f2bf(u0.w);
        o1.x=f2bf(u1.x); o1.y=f2bf(u1.y); o1.z=f2bf(u1.z); o1.w=f2bf(u1.w);
        *(ushort4*)(&As[r*LDP + c])     = o0;
        *(ushort4*)(&As[r*LDP + c + 4]) = o1;
      }
    } else {
      const unsigned short* Asrc = hb + (kk - NF);
      #pragma unroll
      for (int p = 0; p < 2; p++){
        int f = p*256 + t;
        int r = f >> 2, c = (f & 3) * 8;
        int gr = m0 + r; if (gr > M-1) gr = M-1;
        int4 v = *(const int4*)(Asrc + (size_t)gr*NF + c);
        *(int4*)(&As[r*LDP + c]) = v;
      }
    }
    #pragma unroll
    for (int p = 0; p < 2; p++){
      int f = p*256 + t;
      int r = f >> 2, c = (f & 3) * 8;
      int4 v = *(const int4*)(Wt + (size_t)(n0 + r)*KTOT + kk + c);
      *(int4*)(&Bs[r*LDP + c]) = v;
    }
    __syncthreads();
    bf16x8 af[4], bfr[4];
    #pragma unroll
    for (int mi=0;mi<4;mi++)
      af[mi] = *(const bf16x8*)(&As[(wm*64 + mi*16 + lrow)*LDP + k8]);
    #pragma unroll
    for (int ni=0;ni<4;ni++)
      bfr[ni] = *(const bf16x8*)(&Bs[(wn*64 + ni*16 + lrow)*LDP + k8]);
    #pragma unroll
    for (int mi=0;mi<4;mi++)
      #pragma unroll
      for (int ni=0;ni<4;ni++)
        acc[mi][ni] = __builtin_amdgcn_mfma_f32_16x16x32_bf16(af[mi], bfr[ni], acc[mi][ni], 0, 0, 0);
  }

  #pragma unroll
  for (int ni=0;ni<4;ni++){
    int cn = n0 + wn*64 + ni*16 + lrow;
    float bv = bias[cn];
    #pragma unroll
    for (int mi=0;mi<4;mi++){
      #pragma unroll
      for (int r=0;r<4;r++){
        int rm = m0 + wm*64 + mi*16 + (lane>>4)*4 + r;
        if (rm < M){
          float v = acc[mi][ni][r] + bv;
          out[(size_t)rm*NH + cn] = v > 0.f ? v : 0.f;
        }
      }
    }
  }
}

extern "C" void kernel_launch(void* const* d_in, const int* in_sizes, int n_in,
                              void* d_out, int out_size, void* d_ws, size_t ws_size,
                              hipStream_t stream){
  const float* x      = (const float*)d_in[0];
  const float* Wself  = (const float*)d_in[1];
  const float* Wneigh = (const float*)d_in[2];
  const float* bias   = (const float*)d_in[3];
  const int*   esrc   = (const int*)d_in[4];
  const int*   edst   = (const int*)d_in[5];
  const int nn = in_sizes[0] / NF;   // 100000
  const int ne = in_sizes[4];        // 3200000

  // workspace carve-up (~104 MB total)
  char* w = (char*)d_ws;
  auto alloc = [&](size_t bytes)->char*{
    char* p = w; w += (bytes + 511) & ~size_t(511); return p;
  };
  unsigned char*  xq  = (unsigned char*)alloc((size_t)nn*NF);      // fp8 x, 25.6 MB
  unsigned short* hb  = (unsigned short*)alloc((size_t)nn*NF*2);   // bf16 h_neigh, 51.2 MB
  int* col            = (int*)alloc((size_t)ne*4);                 // 12.8 MB
  int* rank           = (int*)alloc((size_t)ne*4);                 // 12.8 MB
  int* deg            = (int*)alloc((size_t)nn*4);
  int* off            = (int*)alloc((size_t)(nn+1)*4);
  unsigned short* Wt  = (unsigned short*)alloc((size_t)NH*KTOT*2);
  int* partial        = (int*)alloc(4096);

  hipMemsetAsync(deg, 0, (size_t)nn*4, stream);

  k_cvt_xq<<<2048, 256, 0, stream>>>(x, (unsigned int*)xq, nn*NF/8);
  k_cvt_w<<<(NH*KTOT + 255)/256, 256, 0, stream>>>(Wself, Wneigh, Wt);
  k_rank<<<2048, 256, 0, stream>>>(edst, deg, rank, ne);
  int nb = (nn + 1023) / 1024;  // 98
  k_partial<<<nb, 256, 0, stream>>>(deg, partial, nn);
  k_scanp<<<1, 128, 0, stream>>>(partial, nb);
  k_scanapply<<<nb, 256, 0, stream>>>(deg, partial, off, nn, ne);
  k_scatter<<<2048, 256, 0, stream>>>(esrc, edst, rank, off, col, ne);
  k_agg<<<(nn + 3)/4, 256, 0, stream>>>(xq, off, col, hb, nn);
  dim3 gg((nn + BM - 1)/BM, NH/BN);
  k_gemm<<<gg, 256, 0, stream>>>(x, hb, Wt, bias, (float*)d_out, nn);
}

// Round 3
// 350.786 us; speedup vs baseline: 1.8640x; 1.3198x over previous
//
#include <hip/hip_runtime.h>
#include <stdint.h>

typedef __attribute__((ext_vector_type(8))) short bf16x8;
typedef __attribute__((ext_vector_type(4))) float f32x4;
typedef __attribute__((ext_vector_type(2))) float f32x2;

#define NF 256
#define NH 256
#define KTOT 512
#define BM 128
#define BN 128
#define BK 32
#define LDP 40   // padded LDS row stride (elems): 80B -> bank-conflict-light
#define EB 256   // edge blocks for bucket sort
#define NBIN 512 // high-bit buckets (dst>>8), covers 131072 >= 100000 nodes

static __device__ __forceinline__ float bf2f(unsigned short u){
  union { unsigned int i; float f; } v; v.i = ((unsigned int)u) << 16; return v.f;
}
static __device__ __forceinline__ unsigned short f2bf(float f){
  union { float f; unsigned int u; } v; v.f = f;
  unsigned int r = v.u + 0x7fffu + ((v.u >> 16) & 1u);   // RNE
  return (unsigned short)(r >> 16);
}
// f32 -> OCP e4m3fn (RNE, FTZ below 2^-6, saturate at 448)
static __device__ __forceinline__ unsigned int f2e4(float f){
  union { float f; unsigned int u; } v; v.f = f;
  unsigned int s = v.u >> 31;
  unsigned int mag = v.u & 0x7fffffffu;
  if (mag > 0x43E00000u) mag = 0x43E00000u;             // clamp to 448
  unsigned int r = mag + 0x7ffffu + ((mag >> 20) & 1u); // RNE at 3 mantissa bits
  if (r < 0x3C800000u) return 0u;                       // below 2^-6 -> 0
  return (s << 7) | (((r >> 20) - 960u) & 0x7fu);
}

// ---- K1: x f32 -> fp8 e4m3 (8 elems/thread) ----
__global__ void k_cvt_xq(const float* __restrict__ x, unsigned int* __restrict__ xq, int n8){
  for (int i = blockIdx.x*blockDim.x + threadIdx.x; i < n8; i += gridDim.x*blockDim.x){
    const float4* p = (const float4*)(x + (size_t)i*8);
    float4 a = p[0], b = p[1];
    unsigned int w0 = f2e4(a.x) | (f2e4(a.y)<<8) | (f2e4(a.z)<<16) | (f2e4(a.w)<<24);
    unsigned int w1 = f2e4(b.x) | (f2e4(b.y)<<8) | (f2e4(b.z)<<16) | (f2e4(b.w)<<24);
    uint2 o; o.x = w0; o.y = w1;
    ((uint2*)xq)[i] = o;
  }
}

// ---- K2: build transposed+concat weight Wt[n][k] = k<256 ? Ws[k][n] : Wn[k-256][n] ----
__global__ void k_cvt_w(const float* __restrict__ Ws, const float* __restrict__ Wn,
                        unsigned short* __restrict__ Wt){
  int t = blockIdx.x*blockDim.x + threadIdx.x;
  if (t >= NH*KTOT) return;
  int n = t >> 9, k = t & 511;
  float v = (k < NF) ? Ws[(size_t)k*NH + n] : Wn[(size_t)(k-NF)*NH + n];
  Wt[t] = (unsigned short)f2bf(v);
}

// ---- S1: per-block 512-bin LDS histogram of dst>>8 -> H[bin*EB + blk] ----
__global__ void __launch_bounds__(256) k_bhist(const int* __restrict__ dst,
                                               int* __restrict__ H, int ne){
  __shared__ int lh[NBIN];
  int blk = blockIdx.x, t = threadIdx.x;
  for (int i = t; i < NBIN; i += 256) lh[i] = 0;
  __syncthreads();
  int chunk = (ne + EB - 1) / EB;
  int e0 = blk * chunk, e1 = ne < e0 + chunk ? ne : e0 + chunk;
  for (int e = e0 + t; e < e1; e += 256)
    atomicAdd(&lh[((unsigned)dst[e]) >> 8], 1);
  __syncthreads();
  for (int i = t; i < NBIN; i += 256) H[i*EB + blk] = lh[i];
}

// ---- K4a: per-block (1024-chunk) sums ----
__global__ void k_partial(const int* __restrict__ deg, int* __restrict__ partial, int n){
  __shared__ int sm[256];
  int b = blockIdx.x, t = threadIdx.x;
  int i0 = b*1024 + t*4;
  int s = 0;
  if (i0 + 3 < n){ int4 v = *(const int4*)(deg + i0); s = v.x+v.y+v.z+v.w; }
  else { for (int j=0;j<4;j++) if (i0+j < n) s += deg[i0+j]; }
  sm[t] = s; __syncthreads();
  for (int d = 128; d > 0; d >>= 1){ if (t < d) sm[t] += sm[t+d]; __syncthreads(); }
  if (t == 0) partial[b] = sm[0];
}

// ---- K4b: exclusive scan of partials (1 block; nb <= 128) ----
__global__ void k_scanp(int* __restrict__ partial, int nb){
  __shared__ int sm[128];
  int t = threadIdx.x;
  int v = (t < nb) ? partial[t] : 0;
  sm[t] = v; __syncthreads();
  for (int d = 1; d < 128; d <<= 1){
    int u = (t >= d) ? sm[t-d] : 0; __syncthreads();
    sm[t] += u; __syncthreads();
  }
  if (t < nb) partial[t] = sm[t] - v;
}

// ---- K4c: apply scan -> exclusive prefix (out[i]), out[n] = ne ----
__global__ void k_scanapply(const int* __restrict__ deg, const int* __restrict__ partial,
                            int* __restrict__ off, int n, int ne){
  __shared__ int sm[256];
  int b = blockIdx.x, t = threadIdx.x;
  int i0 = b*1024 + t*4;
  int d0=0,d1=0,d2=0,d3=0;
  if (i0 + 3 < n){ int4 v = *(const int4*)(deg + i0); d0=v.x; d1=v.y; d2=v.z; d3=v.w; }
  else { if(i0<n)d0=deg[i0]; if(i0+1<n)d1=deg[i0+1]; if(i0+2<n)d2=deg[i0+2]; if(i0+3<n)d3=deg[i0+3]; }
  int s = d0+d1+d2+d3;
  sm[t] = s; __syncthreads();
  for (int d = 1; d < 256; d <<= 1){
    int u = (t >= d) ? sm[t-d] : 0; __syncthreads();
    sm[t] += u; __syncthreads();
  }
  int run = partial[b] + sm[t] - s;
  if (i0   < n) off[i0]   = run; run += d0;
  if (i0+1 < n) off[i0+1] = run; run += d1;
  if (i0+2 < n) off[i0+2] = run; run += d2;
  if (i0+3 < n) off[i0+3] = run;
  if (b == 0 && t == 0) off[n] = ne;
}

// ---- S3: scatter edges to buckets, rank via LDS atomics; payload (src<<8)|(dst&255) ----
__global__ void __launch_bounds__(256) k_bscat(const int* __restrict__ src,
                                               const int* __restrict__ dst,
                                               const int* __restrict__ base,
                                               unsigned int* __restrict__ bkt, int ne){
  __shared__ int lc[NBIN];
  __shared__ int lb[NBIN];
  int blk = blockIdx.x, t = threadIdx.x;
  for (int i = t; i < NBIN; i += 256){ lc[i] = 0; lb[i] = base[i*EB + blk]; }
  __syncthreads();
  int chunk = (ne + EB - 1) / EB;
  int e0 = blk * chunk, e1 = ne < e0 + chunk ? ne : e0 + chunk;
  for (int e = e0 + t; e < e1; e += 256){
    int d = dst[e];
    int bin = ((unsigned)d) >> 8;
    int p = lb[bin] + atomicAdd(&lc[bin], 1);
    bkt[p] = (((unsigned)src[e]) << 8) | ((unsigned)d & 255u);
  }
}

// ---- S4: one block per bucket -> exact CSR (off, col), all-LDS binning ----
__global__ void __launch_bounds__(256) k_csr(const unsigned int* __restrict__ bkt,
                                             const int* __restrict__ base,
                                             int* __restrict__ off, int* __restrict__ col,
                                             int nn, int ne){
  __shared__ int lh[256], sc[256], se[256], lc[256];
  int b = blockIdx.x, t = threadIdx.x;
  int n0 = base[b*EB], n1 = base[(b+1)*EB];
  lh[t] = 0; lc[t] = 0;
  __syncthreads();
  for (int e = n0 + t; e < n1; e += 256)
    atomicAdd(&lh[bkt[e] & 255u], 1);
  __syncthreads();
  int v = lh[t];
  sc[t] = v; __syncthreads();
  for (int d = 1; d < 256; d <<= 1){
    int u = (t >= d) ? sc[t-d] : 0; __syncthreads();
    sc[t] += u; __syncthreads();
  }
  int excl = sc[t] - v;
  se[t] = excl;
  int node = b*256 + t;
  if (node <= nn) off[node] = n0 + excl;   // node==nn lands in the tail bucket -> off[nn]=ne
  __syncthreads();
  for (int e = n0 + t; e < n1; e += 256){
    unsigned u = bkt[e];
    int low = (int)(u & 255u);
    int r = atomicAdd(&lc[low], 1);
    col[n0 + se[low] + r] = (int)(u >> 8);
  }
}

// ---- fp8x4 word -> 4 f32 accumulate ----
static __device__ __forceinline__ void acc4(unsigned int v, float& a0, float& a1, float& a2, float& a3){
#if __has_builtin(__builtin_amdgcn_cvt_pk_f32_fp8)
  f32x2 lo = __builtin_amdgcn_cvt_pk_f32_fp8((int)v, false);
  f32x2 hi = __builtin_amdgcn_cvt_pk_f32_fp8((int)v, true);
  a0 += lo[0]; a1 += lo[1]; a2 += hi[0]; a3 += hi[1];
#else
  #pragma unroll
  for (int j = 0; j < 4; j++){
    unsigned int b = (v >> (8*j)) & 0xffu;
    unsigned int tt = b & 0x7fu;
    union { unsigned int u; float f; } w;
    w.u = ((tt + 960u) << 20) | ((b & 0x80u) << 24);
    float f = tt ? w.f : 0.f;
    if (j==0) a0 += f; else if (j==1) a1 += f; else if (j==2) a2 += f; else a3 += f;
  }
#endif
}

// ---- K6: pull-aggregation over fp8 x, one wave per dst node, mean -> hb (bf16) ----
__global__ void __launch_bounds__(256) k_agg(const unsigned char* __restrict__ xq,
                                             const int* __restrict__ off,
                                             const int* __restrict__ col,
                                             unsigned short* __restrict__ hb, int n){
  int w = threadIdx.x >> 6;
  int lane = threadIdx.x & 63;
  int node = blockIdx.x*4 + w;
  if (node >= n) return;
  int e0 = off[node], e1 = off[node+1];
  float a0=0.f, a1=0.f, a2=0.f, a3=0.f;
  int e = e0;
  for (; e + 3 < e1; e += 4){
    int s0 = col[e], s1 = col[e+1], s2 = col[e+2], s3 = col[e+3];
    unsigned int v0 = ((const unsigned int*)(xq + (size_t)s0*NF))[lane];
    unsigned int v1 = ((const unsigned int*)(xq + (size_t)s1*NF))[lane];
    unsigned int v2 = ((const unsigned int*)(xq + (size_t)s2*NF))[lane];
    unsigned int v3 = ((const unsigned int*)(xq + (size_t)s3*NF))[lane];
    acc4(v0, a0,a1,a2,a3);
    acc4(v1, a0,a1,a2,a3);
    acc4(v2, a0,a1,a2,a3);
    acc4(v3, a0,a1,a2,a3);
  }
  for (; e < e1; e++){
    int s0 = col[e];
    unsigned int v0 = ((const unsigned int*)(xq + (size_t)s0*NF))[lane];
    acc4(v0, a0,a1,a2,a3);
  }
  float inv = 1.f / (float)((e1 - e0) > 1 ? (e1 - e0) : 1);
  ushort4 o;
  o.x = f2bf(a0*inv); o.y = f2bf(a1*inv); o.z = f2bf(a2*inv); o.w = f2bf(a3*inv);
  ((ushort4*)(hb + (size_t)node*NF))[lane] = o;
}

// ---- K7: out = relu([x, h] @ Wt^T + b); A self-half staged from f32 x, neigh-half from bf16 hb ----
__global__ void __launch_bounds__(256) k_gemm(const float* __restrict__ xf,
                                              const unsigned short* __restrict__ hb,
                                              const unsigned short* __restrict__ Wt,
                                              const float* __restrict__ bias,
                                              float* __restrict__ out, int M){
  __shared__ unsigned short As[BM*LDP];
  __shared__ unsigned short Bs[BN*LDP];
  int t = threadIdx.x;
  int m0 = blockIdx.x * BM;
  int n0 = blockIdx.y * BN;
  int w = t >> 6, lane = t & 63;
  int wm = w >> 1, wn = w & 1;
  int lrow = lane & 15, k8 = (lane >> 4) * 8;

  f32x4 acc[4][4];
  #pragma unroll
  for (int i=0;i<4;i++)
    #pragma unroll
    for (int j=0;j<4;j++) acc[i][j] = (f32x4){0.f,0.f,0.f,0.f};

  for (int kk = 0; kk < KTOT; kk += BK){
    __syncthreads();
    if (kk < NF){
      #pragma unroll
      for (int p = 0; p < 2; p++){
        int f = p*256 + t;
        int r = f >> 2, c = (f & 3) * 8;
        int gr = m0 + r; if (gr > M-1) gr = M-1;
        const float* src = xf + (size_t)gr*NF + kk + c;
        float4 u0 = *(const float4*)src;
        float4 u1 = *(const float4*)(src + 4);
        ushort4 o0, o1;
        o0.x=f2bf(u0.x); o0.y=f2bf(u0.y); o0.z=f2bf(u0.z); o0.w=f2bf(u0.w);
        o1.x=f2bf(u1.x); o1.y=f2bf(u1.y); o1.z=f2bf(u1.z); o1.w=f2bf(u1.w);
        *(ushort4*)(&As[r*LDP + c])     = o0;
        *(ushort4*)(&As[r*LDP + c + 4]) = o1;
      }
    } else {
      const unsigned short* Asrc = hb + (kk - NF);
      #pragma unroll
      for (int p = 0; p < 2; p++){
        int f = p*256 + t;
        int r = f >> 2, c = (f & 3) * 8;
        int gr = m0 + r; if (gr > M-1) gr = M-1;
        int4 v = *(const int4*)(Asrc + (size_t)gr*NF + c);
        *(int4*)(&As[r*LDP + c]) = v;
      }
    }
    #pragma unroll
    for (int p = 0; p < 2; p++){
      int f = p*256 + t;
      int r = f >> 2, c = (f & 3) * 8;
      int4 v = *(const int4*)(Wt + (size_t)(n0 + r)*KTOT + kk + c);
      *(int4*)(&Bs[r*LDP + c]) = v;
    }
    __syncthreads();
    bf16x8 af[4], bfr[4];
    #pragma unroll
    for (int mi=0;mi<4;mi++)
      af[mi] = *(const bf16x8*)(&As[(wm*64 + mi*16 + lrow)*LDP + k8]);
    #pragma unroll
    for (int ni=0;ni<4;ni++)
      bfr[ni] = *(const bf16x8*)(&Bs[(wn*64 + ni*16 + lrow)*LDP + k8]);
    #pragma unroll
    for (int mi=0;mi<4;mi++)
      #pragma unroll
      for (int ni=0;ni<4;ni++)
        acc[mi][ni] = __builtin_amdgcn_mfma_f32_16x16x32_bf16(af[mi], bfr[ni], acc[mi][ni], 0, 0, 0);
  }

  #pragma unroll
  for (int ni=0;ni<4;ni++){
    int cn = n0 + wn*64 + ni*16 + lrow;
    float bv = bias[cn];
    #pragma unroll
    for (int mi=0;mi<4;mi++){
      #pragma unroll
      for (int r=0;r<4;r++){
        int rm = m0 + wm*64 + mi*16 + (lane>>4)*4 + r;
        if (rm < M){
          float v = acc[mi][ni][r] + bv;
          out[(size_t)rm*NH + cn] = v > 0.f ? v : 0.f;
        }
      }
    }
  }
}

extern "C" void kernel_launch(void* const* d_in, const int* in_sizes, int n_in,
                              void* d_out, int out_size, void* d_ws, size_t ws_size,
                              hipStream_t stream){
  const float* x      = (const float*)d_in[0];
  const float* Wself  = (const float*)d_in[1];
  const float* Wneigh = (const float*)d_in[2];
  const float* bias   = (const float*)d_in[3];
  const int*   esrc   = (const int*)d_in[4];
  const int*   edst   = (const int*)d_in[5];
  const int nn = in_sizes[0] / NF;   // 100000
  const int ne = in_sizes[4];        // 3200000

  // workspace carve-up (~104 MB total)
  char* w = (char*)d_ws;
  auto alloc = [&](size_t bytes)->char*{
    char* p = w; w += (bytes + 511) & ~size_t(511); return p;
  };
  unsigned char*  xq  = (unsigned char*)alloc((size_t)nn*NF);      // fp8 x, 25.6 MB
  unsigned short* hb  = (unsigned short*)alloc((size_t)nn*NF*2);   // bf16 h_neigh, 51.2 MB
  unsigned int* bkt   = (unsigned int*)alloc((size_t)ne*4);        // bucketed edges, 12.8 MB
  int* col            = (int*)alloc((size_t)ne*4);                 // CSR col, 12.8 MB
  int* H              = (int*)alloc((size_t)(NBIN*EB + 1)*4);      // 512x256 hist, 524 KB
  int* base           = (int*)alloc((size_t)(NBIN*EB + 1)*4);      // scanned hist
  int* off            = (int*)alloc((size_t)(nn+1)*4);
  unsigned short* Wt  = (unsigned short*)alloc((size_t)NH*KTOT*2);
  int* partial        = (int*)alloc(4096);

  const int nH = NBIN*EB;            // 131072
  const int nb = nH / 1024;          // 128

  k_cvt_xq<<<2048, 256, 0, stream>>>(x, (unsigned int*)xq, nn*NF/8);
  k_cvt_w<<<(NH*KTOT + 255)/256, 256, 0, stream>>>(Wself, Wneigh, Wt);
  k_bhist<<<EB, 256, 0, stream>>>(edst, H, ne);
  k_partial<<<nb, 256, 0, stream>>>(H, partial, nH);
  k_scanp<<<1, 128, 0, stream>>>(partial, nb);
  k_scanapply<<<nb, 256, 0, stream>>>(H, partial, base, nH, ne);
  k_bscat<<<EB, 256, 0, stream>>>(esrc, edst, base, bkt, ne);
  k_csr<<<NBIN, 256, 0, stream>>>(bkt, base, off, col, nn, ne);
  k_agg<<<(nn + 3)/4, 256, 0, stream>>>(xq, off, col, hb, nn);
  dim3 gg((nn + BM - 1)/BM, NH/BN);
  k_gemm<<<gg, 256, 0, stream>>>(x, hb, Wt, bias, (float*)d_out, nn);
}

// Round 4
// 340.802 us; speedup vs baseline: 1.9186x; 1.0293x over previous
//
#include <hip/hip_runtime.h>
#include <stdint.h>

typedef __attribute__((ext_vector_type(8))) short bf16x8;
typedef __attribute__((ext_vector_type(4))) float f32x4;
typedef __attribute__((ext_vector_type(2))) float f32x2;

#define NF 256
#define NH 256
#define KTOT 512
#define BM 128
#define BN 128
#define BK2 64
#define LDP2 72  // padded LDS row stride for BK=64 (144B: 4-bank row skew, <=2-way)
#define EB 256   // edge blocks for bucket sort
#define NBIN 512 // high-bit buckets (dst>>8), covers 131072 >= 100000 nodes

static __device__ __forceinline__ unsigned short f2bf(float f){
  union { float f; unsigned int u; } v; v.f = f;
  unsigned int r = v.u + 0x7fffu + ((v.u >> 16) & 1u);   // RNE
  return (unsigned short)(r >> 16);
}
// f32 -> OCP e4m3fn (RNE, FTZ below 2^-6, saturate at 448)
static __device__ __forceinline__ unsigned int f2e4(float f){
  union { float f; unsigned int u; } v; v.f = f;
  unsigned int s = v.u >> 31;
  unsigned int mag = v.u & 0x7fffffffu;
  if (mag > 0x43E00000u) mag = 0x43E00000u;             // clamp to 448
  unsigned int r = mag + 0x7ffffu + ((mag >> 20) & 1u); // RNE at 3 mantissa bits
  if (r < 0x3C800000u) return 0u;                       // below 2^-6 -> 0
  return (s << 7) | (((r >> 20) - 960u) & 0x7fu);
}

// ---- K1: x f32 -> fp8 e4m3 (8 elems/thread) ----
__global__ void k_cvt_xq(const float* __restrict__ x, unsigned int* __restrict__ xq, int n8){
  for (int i = blockIdx.x*blockDim.x + threadIdx.x; i < n8; i += gridDim.x*blockDim.x){
    const float4* p = (const float4*)(x + (size_t)i*8);
    float4 a = p[0], b = p[1];
    unsigned int w0 = f2e4(a.x) | (f2e4(a.y)<<8) | (f2e4(a.z)<<16) | (f2e4(a.w)<<24);
    unsigned int w1 = f2e4(b.x) | (f2e4(b.y)<<8) | (f2e4(b.z)<<16) | (f2e4(b.w)<<24);
    uint2 o; o.x = w0; o.y = w1;
    ((uint2*)xq)[i] = o;
  }
}

// ---- K2: build transposed+concat weight Wt[n][k] = k<256 ? Ws[k][n] : Wn[k-256][n] ----
__global__ void k_cvt_w(const float* __restrict__ Ws, const float* __restrict__ Wn,
                        unsigned short* __restrict__ Wt){
  int t = blockIdx.x*blockDim.x + threadIdx.x;
  if (t >= NH*KTOT) return;
  int n = t >> 9, k = t & 511;
  float v = (k < NF) ? Ws[(size_t)k*NH + n] : Wn[(size_t)(k-NF)*NH + n];
  Wt[t] = (unsigned short)f2bf(v);
}

// ---- S1: per-block 512-bin LDS histogram of dst>>8 -> H[bin*EB + blk] ----
__global__ void __launch_bounds__(256) k_bhist(const int* __restrict__ dst,
                                               int* __restrict__ H, int ne){
  __shared__ int lh[NBIN];
  int blk = blockIdx.x, t = threadIdx.x;
  for (int i = t; i < NBIN; i += 256) lh[i] = 0;
  __syncthreads();
  int chunk = (ne + EB - 1) / EB;
  int e0 = blk * chunk, e1 = ne < e0 + chunk ? ne : e0 + chunk;
  for (int e = e0 + t; e < e1; e += 256)
    atomicAdd(&lh[((unsigned)dst[e]) >> 8], 1);
  __syncthreads();
  for (int i = t; i < NBIN; i += 256) H[i*EB + blk] = lh[i];
}

// ---- K4a: per-block (1024-chunk) sums ----
__global__ void k_partial(const int* __restrict__ deg, int* __restrict__ partial, int n){
  __shared__ int sm[256];
  int b = blockIdx.x, t = threadIdx.x;
  int i0 = b*1024 + t*4;
  int s = 0;
  if (i0 + 3 < n){ int4 v = *(const int4*)(deg + i0); s = v.x+v.y+v.z+v.w; }
  else { for (int j=0;j<4;j++) if (i0+j < n) s += deg[i0+j]; }
  sm[t] = s; __syncthreads();
  for (int d = 128; d > 0; d >>= 1){ if (t < d) sm[t] += sm[t+d]; __syncthreads(); }
  if (t == 0) partial[b] = sm[0];
}

// ---- K4b: exclusive scan of partials (1 block; nb <= 128) ----
__global__ void k_scanp(int* __restrict__ partial, int nb){
  __shared__ int sm[128];
  int t = threadIdx.x;
  int v = (t < nb) ? partial[t] : 0;
  sm[t] = v; __syncthreads();
  for (int d = 1; d < 128; d <<= 1){
    int u = (t >= d) ? sm[t-d] : 0; __syncthreads();
    sm[t] += u; __syncthreads();
  }
  if (t < nb) partial[t] = sm[t] - v;
}

// ---- K4c: apply scan -> exclusive prefix ----
__global__ void k_scanapply(const int* __restrict__ deg, const int* __restrict__ partial,
                            int* __restrict__ off, int n, int ne){
  __shared__ int sm[256];
  int b = blockIdx.x, t = threadIdx.x;
  int i0 = b*1024 + t*4;
  int d0=0,d1=0,d2=0,d3=0;
  if (i0 + 3 < n){ int4 v = *(const int4*)(deg + i0); d0=v.x; d1=v.y; d2=v.z; d3=v.w; }
  else { if(i0<n)d0=deg[i0]; if(i0+1<n)d1=deg[i0+1]; if(i0+2<n)d2=deg[i0+2]; if(i0+3<n)d3=deg[i0+3]; }
  int s = d0+d1+d2+d3;
  sm[t] = s; __syncthreads();
  for (int d = 1; d < 256; d <<= 1){
    int u = (t >= d) ? sm[t-d] : 0; __syncthreads();
    sm[t] += u; __syncthreads();
  }
  int run = partial[b] + sm[t] - s;
  if (i0   < n) off[i0]   = run; run += d0;
  if (i0+1 < n) off[i0+1] = run; run += d1;
  if (i0+2 < n) off[i0+2] = run; run += d2;
  if (i0+3 < n) off[i0+3] = run;
  if (b == 0 && t == 0) off[n] = ne;
}

// ---- S3: scatter edges to buckets, rank via LDS atomics; payload (src<<8)|(dst&255) ----
__global__ void __launch_bounds__(256) k_bscat(const int* __restrict__ src,
                                               const int* __restrict__ dst,
                                               const int* __restrict__ base,
                                               unsigned int* __restrict__ bkt, int ne){
  __shared__ int lc[NBIN];
  __shared__ int lb[NBIN];
  int blk = blockIdx.x, t = threadIdx.x;
  for (int i = t; i < NBIN; i += 256){ lc[i] = 0; lb[i] = base[i*EB + blk]; }
  __syncthreads();
  int chunk = (ne + EB - 1) / EB;
  int e0 = blk * chunk, e1 = ne < e0 + chunk ? ne : e0 + chunk;
  for (int e = e0 + t; e < e1; e += 256){
    int d = dst[e];
    int bin = ((unsigned)d) >> 8;
    int p = lb[bin] + atomicAdd(&lc[bin], 1);
    bkt[p] = (((unsigned)src[e]) << 8) | ((unsigned)d & 255u);
  }
}

// ---- S4: one block per bucket -> exact CSR (off, col), all-LDS binning ----
__global__ void __launch_bounds__(256) k_csr(const unsigned int* __restrict__ bkt,
                                             const int* __restrict__ base,
                                             int* __restrict__ off, int* __restrict__ col,
                                             int nn, int ne){
  __shared__ int lh[256], sc[256], se[256], lc[256];
  int b = blockIdx.x, t = threadIdx.x;
  int n0 = base[b*EB], n1 = base[(b+1)*EB];
  lh[t] = 0; lc[t] = 0;
  __syncthreads();
  for (int e = n0 + t; e < n1; e += 256)
    atomicAdd(&lh[bkt[e] & 255u], 1);
  __syncthreads();
  int v = lh[t];
  sc[t] = v; __syncthreads();
  for (int d = 1; d < 256; d <<= 1){
    int u = (t >= d) ? sc[t-d] : 0; __syncthreads();
    sc[t] += u; __syncthreads();
  }
  int excl = sc[t] - v;
  se[t] = excl;
  int node = b*256 + t;
  if (node <= nn) off[node] = n0 + excl;
  __syncthreads();
  for (int e = n0 + t; e < n1; e += 256){
    unsigned u = bkt[e];
    int low = (int)(u & 255u);
    int r = atomicAdd(&lc[low], 1);
    col[n0 + se[low] + r] = (int)(u >> 8);
  }
}

// ---- fp8x4 word -> 4 f32 accumulate ----
static __device__ __forceinline__ void acc4(unsigned int v, float& a0, float& a1, float& a2, float& a3){
#if __has_builtin(__builtin_amdgcn_cvt_pk_f32_fp8)
  f32x2 lo = __builtin_amdgcn_cvt_pk_f32_fp8((int)v, false);
  f32x2 hi = __builtin_amdgcn_cvt_pk_f32_fp8((int)v, true);
  a0 += lo[0]; a1 += lo[1]; a2 += hi[0]; a3 += hi[1];
#else
  #pragma unroll
  for (int j = 0; j < 4; j++){
    unsigned int b = (v >> (8*j)) & 0xffu;
    unsigned int tt = b & 0x7fu;
    union { unsigned int u; float f; } w;
    w.u = ((tt + 960u) << 20) | ((b & 0x80u) << 24);
    float f = tt ? w.f : 0.f;
    if (j==0) a0 += f; else if (j==1) a1 += f; else if (j==2) a2 += f; else a3 += f;
  }
#endif
}
// fp8x4 -> 4 bf16 (lossless: e4m3 subset of bf16)
static __device__ __forceinline__ ushort4 dec8(unsigned int v){
#if __has_builtin(__builtin_amdgcn_cvt_pk_f32_fp8)
  f32x2 lo = __builtin_amdgcn_cvt_pk_f32_fp8((int)v, false);
  f32x2 hi = __builtin_amdgcn_cvt_pk_f32_fp8((int)v, true);
  ushort4 o; o.x=f2bf(lo[0]); o.y=f2bf(lo[1]); o.z=f2bf(hi[0]); o.w=f2bf(hi[1]);
  return o;
#else
  ushort4 o; unsigned short r[4];
  #pragma unroll
  for (int j = 0; j < 4; j++){
    unsigned int b = (v >> (8*j)) & 0xffu;
    unsigned int tt = b & 0x7fu;
    union { unsigned int u; float f; } w;
    w.u = ((tt + 960u) << 20) | ((b & 0x80u) << 24);
    r[j] = tt ? f2bf(w.f) : (unsigned short)0;
  }
  o.x=r[0]; o.y=r[1]; o.z=r[2]; o.w=r[3];
  return o;
#endif
}

// ---- K6: pull-aggregation over fp8 x; wave/node; scalar-base gathers, 8-deep; mean -> hq (fp8) ----
__global__ void __launch_bounds__(256) k_agg(const unsigned int* __restrict__ xw,
                                             const int* __restrict__ off,
                                             const int* __restrict__ col,
                                             unsigned int* __restrict__ hq, int n){
  int w = threadIdx.x >> 6;
  int lane = threadIdx.x & 63;
  int node = blockIdx.x*4 + w;
  if (node >= n) return;
  int e0 = off[node], e1 = off[node+1];
  int deg = e1 - e0;
  float a0=0.f, a1=0.f, a2=0.f, a3=0.f;
  for (int c0 = 0; c0 < deg; c0 += 64){
    int len = deg - c0; if (len > 64) len = 64;
    int cv = 0;
    if (lane < len) cv = col[e0 + c0 + lane];   // one vector load covers 64 edges
    int i = 0;
    for (; i + 8 <= len; i += 8){
      int s0 = __builtin_amdgcn_readlane(cv, i+0);
      int s1 = __builtin_amdgcn_readlane(cv, i+1);
      int s2 = __builtin_amdgcn_readlane(cv, i+2);
      int s3 = __builtin_amdgcn_readlane(cv, i+3);
      int s4 = __builtin_amdgcn_readlane(cv, i+4);
      int s5 = __builtin_amdgcn_readlane(cv, i+5);
      int s6 = __builtin_amdgcn_readlane(cv, i+6);
      int s7 = __builtin_amdgcn_readlane(cv, i+7);
      unsigned int u0 = xw[(size_t)s0*64 + lane];
      unsigned int u1 = xw[(size_t)s1*64 + lane];
      unsigned int u2 = xw[(size_t)s2*64 + lane];
      unsigned int u3 = xw[(size_t)s3*64 + lane];
      unsigned int u4 = xw[(size_t)s4*64 + lane];
      unsigned int u5 = xw[(size_t)s5*64 + lane];
      unsigned int u6 = xw[(size_t)s6*64 + lane];
      unsigned int u7 = xw[(size_t)s7*64 + lane];
      acc4(u0,a0,a1,a2,a3); acc4(u1,a0,a1,a2,a3);
      acc4(u2,a0,a1,a2,a3); acc4(u3,a0,a1,a2,a3);
      acc4(u4,a0,a1,a2,a3); acc4(u5,a0,a1,a2,a3);
      acc4(u6,a0,a1,a2,a3); acc4(u7,a0,a1,a2,a3);
    }
    for (; i < len; ++i){
      int s = __builtin_amdgcn_readlane(cv, i);
      unsigned int u = xw[(size_t)s*64 + lane];
      acc4(u,a0,a1,a2,a3);
    }
  }
  float inv = 1.f / (float)(deg > 1 ? deg : 1);
  unsigned int o = f2e4(a0*inv) | (f2e4(a1*inv)<<8) | (f2e4(a2*inv)<<16) | (f2e4(a3*inv)<<24);
  hq[(size_t)node*64 + lane] = o;
}

// ---- K7: out = relu([x, h] @ Wt^T + b); BK=64; self from f32 x, neigh from fp8 hq ----
__global__ void __launch_bounds__(256) k_gemm(const float* __restrict__ xf,
                                              const unsigned char* __restrict__ hq,
                                              const unsigned short* __restrict__ Wt,
                                              const float* __restrict__ bias,
                                              float* __restrict__ out, int M){
  __shared__ unsigned short As[BM*LDP2];
  __shared__ unsigned short Bs[BN*LDP2];
  int t = threadIdx.x;
  int m0 = blockIdx.x * BM;
  int n0 = blockIdx.y * BN;
  int w = t >> 6, lane = t & 63;
  int wm = w >> 1, wn = w & 1;
  int lrow = lane & 15, k8 = (lane >> 4) * 8;

  f32x4 acc[4][4];
  #pragma unroll
  for (int i=0;i<4;i++)
    #pragma unroll
    for (int j=0;j<4;j++) acc[i][j] = (f32x4){0.f,0.f,0.f,0.f};

  for (int kk = 0; kk < KTOT; kk += BK2){
    __syncthreads();
    if (kk < NF){
      #pragma unroll
      for (int q = 0; q < 4; q++){
        int chunk = q*256 + t;
        int r = chunk >> 3, c8 = (chunk & 7) * 8;
        int gr = m0 + r; if (gr > M-1) gr = M-1;
        const float* src = xf + (size_t)gr*NF + kk + c8;
        float4 u0 = ((const float4*)src)[0];
        float4 u1 = ((const float4*)src)[1];
        ushort4 o0, o1;
        o0.x=f2bf(u0.x); o0.y=f2bf(u0.y); o0.z=f2bf(u0.z); o0.w=f2bf(u0.w);
        o1.x=f2bf(u1.x); o1.y=f2bf(u1.y); o1.z=f2bf(u1.z); o1.w=f2bf(u1.w);
        *(ushort4*)(&As[r*LDP2 + c8])     = o0;
        *(ushort4*)(&As[r*LDP2 + c8 + 4]) = o1;
      }
    } else {
      #pragma unroll
      for (int q = 0; q < 4; q++){
        int chunk = q*256 + t;
        int r = chunk >> 3, c8 = (chunk & 7) * 8;
        int gr = m0 + r; if (gr > M-1) gr = M-1;
        uint2 v = *(const uint2*)(hq + (size_t)gr*NF + (kk - NF) + c8);
        *(ushort4*)(&As[r*LDP2 + c8])     = dec8(v.x);
        *(ushort4*)(&As[r*LDP2 + c8 + 4]) = dec8(v.y);
      }
    }
    #pragma unroll
    for (int q = 0; q < 4; q++){
      int chunk = q*256 + t;
      int r = chunk >> 3, c8 = (chunk & 7) * 8;
      int4 v = *(const int4*)(Wt + (size_t)(n0 + r)*KTOT + kk + c8);
      *(int4*)(&Bs[r*LDP2 + c8]) = v;
    }
    __syncthreads();
    #pragma unroll
    for (int ks = 0; ks < 2; ks++){
      bf16x8 af[4], bfr[4];
      #pragma unroll
      for (int mi=0;mi<4;mi++)
        af[mi] = *(const bf16x8*)(&As[(wm*64 + mi*16 + lrow)*LDP2 + ks*32 + k8]);
      #pragma unroll
      for (int ni=0;ni<4;ni++)
        bfr[ni] = *(const bf16x8*)(&Bs[(wn*64 + ni*16 + lrow)*LDP2 + ks*32 + k8]);
      #pragma unroll
      for (int mi=0;mi<4;mi++)
        #pragma unroll
        for (int ni=0;ni<4;ni++)
          acc[mi][ni] = __builtin_amdgcn_mfma_f32_16x16x32_bf16(af[mi], bfr[ni], acc[mi][ni], 0, 0, 0);
    }
  }

  #pragma unroll
  for (int ni=0;ni<4;ni++){
    int cn = n0 + wn*64 + ni*16 + lrow;
    float bv = bias[cn];
    #pragma unroll
    for (int mi=0;mi<4;mi++){
      #pragma unroll
      for (int r=0;r<4;r++){
        int rm = m0 + wm*64 + mi*16 + (lane>>4)*4 + r;
        if (rm < M){
          float v = acc[mi][ni][r] + bv;
          out[(size_t)rm*NH + cn] = v > 0.f ? v : 0.f;
        }
      }
    }
  }
}

extern "C" void kernel_launch(void* const* d_in, const int* in_sizes, int n_in,
                              void* d_out, int out_size, void* d_ws, size_t ws_size,
                              hipStream_t stream){
  const float* x      = (const float*)d_in[0];
  const float* Wself  = (const float*)d_in[1];
  const float* Wneigh = (const float*)d_in[2];
  const float* bias   = (const float*)d_in[3];
  const int*   esrc   = (const int*)d_in[4];
  const int*   edst   = (const int*)d_in[5];
  const int nn = in_sizes[0] / NF;   // 100000
  const int ne = in_sizes[4];        // 3200000

  // workspace carve-up (~79 MB total)
  char* w = (char*)d_ws;
  auto alloc = [&](size_t bytes)->char*{
    char* p = w; w += (bytes + 511) & ~size_t(511); return p;
  };
  unsigned char*  xq  = (unsigned char*)alloc((size_t)nn*NF);      // fp8 x, 25.6 MB
  unsigned char*  hq  = (unsigned char*)alloc((size_t)nn*NF);      // fp8 h_neigh, 25.6 MB
  unsigned int* bkt   = (unsigned int*)alloc((size_t)ne*4);        // bucketed edges, 12.8 MB
  int* col            = (int*)alloc((size_t)ne*4);                 // CSR col, 12.8 MB
  int* H              = (int*)alloc((size_t)(NBIN*EB + 1)*4);      // 512x256 hist
  int* base           = (int*)alloc((size_t)(NBIN*EB + 1)*4);      // scanned hist
  int* off            = (int*)alloc((size_t)(nn+1)*4);
  unsigned short* Wt  = (unsigned short*)alloc((size_t)NH*KTOT*2);
  int* partial        = (int*)alloc(4096);

  const int nH = NBIN*EB;            // 131072
  const int nb = nH / 1024;          // 128

  k_cvt_xq<<<2048, 256, 0, stream>>>(x, (unsigned int*)xq, nn*NF/8);
  k_cvt_w<<<(NH*KTOT + 255)/256, 256, 0, stream>>>(Wself, Wneigh, Wt);
  k_bhist<<<EB, 256, 0, stream>>>(edst, H, ne);
  k_partial<<<nb, 256, 0, stream>>>(H, partial, nH);
  k_scanp<<<1, 128, 0, stream>>>(partial, nb);
  k_scanapply<<<nb, 256, 0, stream>>>(H, partial, base, nH, ne);
  k_bscat<<<EB, 256, 0, stream>>>(esrc, edst, base, bkt, ne);
  k_csr<<<NBIN, 256, 0, stream>>>(bkt, base, off, col, nn, ne);
  k_agg<<<(nn + 3)/4, 256, 0, stream>>>((const unsigned int*)xq, off, col, (unsigned int*)hq, nn);
  dim3 gg((nn + BM - 1)/BM, NH/BN);
  k_gemm<<<gg, 256, 0, stream>>>(x, hq, Wt, bias, (float*)d_out, nn);
}